// Round 22
// baseline (410.539 us; speedup 1.0000x reference)
//
#include <hip/hip_runtime.h>
#include <hip/hip_fp16.h>

#define N_NODES  200000
#define N_EDGES  3200000
#define HIDDEN   64
#define N_GRAPHS 4096
#define N_CLASSES 7
#define NBUCK    782          // ceil(N_NODES / 256)
#define BSHIFT   8
#define BMASK    255
#define BCAP     5120         // fixed bucket capacity (E=4096, sigma~64, 16-sigma margin)
#define CPW      16           // nodes (chunk) per wave
#define NCHUNK   (N_NODES / CPW)          // 12500
#define GLAYER   (NCHUNK / 4)             // 3125 blocks of 4 waves

// ---------- init per-bucket cursors to fixed slot bases ----------
__global__ void k_init(int* __restrict__ gcur) {
    int tid = threadIdx.x;
    if (tid < NBUCK) gcur[tid] = tid * BCAP;
}

// ---------- coarse partition, LDS-staged: block-local counting sort into LDS,
//            then bucket-contiguous (coalesced) global writes into fixed slots ----------
#define PT_EPT 32
#define PT_EDGES (256 * PT_EPT)           // 8192 edges per block
__global__ void k_part(const int* __restrict__ src, const int* __restrict__ dst,
                       int* __restrict__ gcur, int* __restrict__ stage) {
    __shared__ int lh[NBUCK];
    __shared__ int lofs[NBUCK];
    __shared__ int lbase[NBUCK];
    __shared__ int lcur[NBUCK];
    __shared__ int tmp[256];
    __shared__ int buf[PT_EDGES];             // 32 KB staged payloads
    __shared__ unsigned short bid[PT_EDGES];  // bucket id per staged slot (NBUCK>255)
    int tid = threadIdx.x;
    for (int i = tid; i < NBUCK; i += 256) { lh[i] = 0; lcur[i] = 0; }
    __syncthreads();
    int base = blockIdx.x * PT_EDGES + tid;
    for (int k = 0; k < PT_EPT; ++k) {
        int e = base + k * 256;
        if (e < N_EDGES) atomicAdd(&lh[dst[e] >> BSHIFT], 1);
    }
    __syncthreads();
    // block scan of 782 bucket counts (4 per thread) -> local offsets; reserve ranges
    int b0 = tid * 4;
    int c0 = (b0 + 0 < NBUCK) ? lh[b0 + 0] : 0;
    int c1 = (b0 + 1 < NBUCK) ? lh[b0 + 1] : 0;
    int c2 = (b0 + 2 < NBUCK) ? lh[b0 + 2] : 0;
    int c3 = (b0 + 3 < NBUCK) ? lh[b0 + 3] : 0;
    int ssum = c0 + c1 + c2 + c3;
    int x = ssum; tmp[tid] = x; __syncthreads();
    for (int o = 1; o < 256; o <<= 1) {
        int y = (tid >= o) ? tmp[tid - o] : 0;
        __syncthreads();
        x += y; tmp[tid] = x;
        __syncthreads();
    }
    int run = x - ssum;
    if (b0 + 0 < NBUCK) { lofs[b0 + 0] = run; if (c0) lbase[b0 + 0] = atomicAdd(&gcur[b0 + 0], c0); run += c0; }
    if (b0 + 1 < NBUCK) { lofs[b0 + 1] = run; if (c1) lbase[b0 + 1] = atomicAdd(&gcur[b0 + 1], c1); run += c1; }
    if (b0 + 2 < NBUCK) { lofs[b0 + 2] = run; if (c2) lbase[b0 + 2] = atomicAdd(&gcur[b0 + 2], c2); run += c2; }
    if (b0 + 3 < NBUCK) { lofs[b0 + 3] = run; if (c3) lbase[b0 + 3] = atomicAdd(&gcur[b0 + 3], c3); run += c3; }
    __syncthreads();
    // scatter into LDS (cheap) instead of global
    for (int k = 0; k < PT_EPT; ++k) {
        int e = base + k * 256;
        if (e < N_EDGES) {
            int d = dst[e], b = d >> BSHIFT;
            int lp = lofs[b] + atomicAdd(&lcur[b], 1);
            buf[lp] = (src[e] << BSHIFT) | (d & BMASK);
            bid[lp] = (unsigned short)b;
        }
    }
    __syncthreads();
    // bucket-contiguous global writes (short coalesced runs)
    int nval = N_EDGES - blockIdx.x * PT_EDGES;
    if (nval > PT_EDGES) nval = PT_EDGES;
    for (int l = tid; l < nval; l += 256) {
        int b = bid[l];
        stage[lbase[b] + (l - lofs[b])] = buf[l];
    }
}

// ---------- per-bucket exact sort + CSR metadata; one node per thread.
//            ZERO-FILLS the bucket gap so downstream over-reads see valid
//            node index 0 (masked out of sums, but in-bounds). ----------
__global__ void k_sort(const int* __restrict__ stage, const int* __restrict__ gcur,
                       int* __restrict__ edges, int* __restrict__ off,
                       int* __restrict__ endv, float* __restrict__ dinv,
                       const float2* __restrict__ x2, float2* __restrict__ xs2) {
    __shared__ int hist[256];
    __shared__ int tmp[256];
    int b = blockIdx.x, tid = threadIdx.x;
    int cb0 = b * BCAP;
    int cb1 = gcur[b];                   // cb0 + bucket count
    hist[tid] = 0;
    __syncthreads();
    for (int j = cb0 + tid; j < cb1; j += 256)
        atomicAdd(&hist[stage[j] & BMASK], 1);
    __syncthreads();
    int c = hist[tid];
    int x = c; tmp[tid] = x; __syncthreads();
    for (int o = 1; o < 256; o <<= 1) {
        int y = (tid >= o) ? tmp[tid - o] : 0;
        __syncthreads();
        x += y; tmp[tid] = x;
        __syncthreads();
    }
    int run = x - c;                     // exclusive prefix: this node's slot base
    int node = (b << BSHIFT) + tid;
    if (node < N_NODES) {
        off[node]  = cb0 + run;
        endv[node] = cb0 + run + c;
        float di = rsqrtf((float)c + 1.0f);   // +1 self loop
        dinv[node] = di;
        float2 xv = x2[node];
        xs2[node] = make_float2(di * xv.x, di * xv.y);
    }
    __syncthreads();
    hist[tid] = run;                     // local cursor start
    __syncthreads();
    for (int j = cb0 + tid; j < cb1; j += 256) {
        int p = stage[j];
        int pos = atomicAdd(&hist[p & BMASK], 1);
        edges[cb0 + pos] = p >> BSHIFT;  // src
    }
    // zero-fill the gap [cb1, cb0+BCAP) — masked over-reads land on node 0
    for (int j = cb1 + tid; j < cb0 + BCAP; j += 256)
        edges[j] = 0;
}

static __device__ __forceinline__ float rdlf(float v, int l) {
    return __uint_as_float(__builtin_amdgcn_readlane(__float_as_uint(v), (unsigned)l));
}
static __device__ __forceinline__ int rdli(int v, int l) {
    return __builtin_amdgcn_readlane(v, (unsigned)l);
}
// fp16 row fragment (4 channels) -> fp32 accumulate
static __device__ __forceinline__ void acc4h(float4& a, uint2 r) {
    __half2 h01 = *reinterpret_cast<const __half2*>(&r.x);
    __half2 h23 = *reinterpret_cast<const __half2*>(&r.y);
    float2 f01 = __half22float2(h01);
    float2 f23 = __half22float2(h23);
    a.x += f01.x; a.y += f01.y; a.z += f23.x; a.w += f23.y;
}

// ---------- layer 1: chunked gather of prescaled x (value-prefetched) + W1 +
//            relu + fused W2, store fp16 prescaled rows ----------
__global__ __launch_bounds__(256, 4)
void k_l1(const int* __restrict__ edges, const int* __restrict__ off,
          const int* __restrict__ endv, const float* __restrict__ dinv,
          const float2* __restrict__ xs2,
          const float* __restrict__ W1, const float* __restrict__ b1,
          const float* __restrict__ W2, __half* __restrict__ Yout) {
    int lane = threadIdx.x & 63;
    int wid = blockIdx.x * 4 + (threadIdx.x >> 6);
    int n0 = wid * CPW;
    if (n0 >= N_NODES) return;
    float w1a = W1[lane], w1b = W1[64 + lane], bb = b1[lane];
    float4 wc[16];
#pragma unroll
    for (int t = 0; t < 16; ++t) {
        wc[t].x = W2[(4 * t + 0) * 64 + lane];
        wc[t].y = W2[(4 * t + 1) * 64 + lane];
        wc[t].z = W2[(4 * t + 2) * 64 + lane];
        wc[t].w = W2[(4 * t + 3) * 64 + lane];
    }
#pragma unroll
    for (int t = 0; t < 16; ++t) {
        asm volatile("" : "+v"(wc[t].x), "+v"(wc[t].y), "+v"(wc[t].z), "+v"(wc[t].w));
    }
    // chunk metadata in lanes 0..15
    int mo = 0, me = 0; float md = 0.0f; float sxx = 0.0f, sxy = 0.0f;
    if (lane < CPW) {
        int nn = n0 + lane;
        mo = off[nn]; me = endv[nn]; md = dinv[nn];
        float2 sv = xs2[nn];
        sxx = sv.x; sxy = sv.y;
    }
    int j0 = rdli(mo, 0);
    int deg0 = rdli(me, 0) - j0;
    int idx = j0 + lane;
    int ev = edges[idx];
    float pxv = 0.0f, pyv = 0.0f;                // prefetched gather values
    if (lane < deg0) {
        float2 v = xs2[ev];
        pxv = v.x; pyv = v.y;
    }
    for (int i = 0; i < CPW; ++i) {
        int n = n0 + i;
        float dn = rdlf(md, i);
        int deg = rdli(me, i) - j0;
        // prefetch next node's edge vector AND its gather values
        int evn = 0; int j0n = 0;
        float pxn = 0.0f, pyn = 0.0f;
        if (i < CPW - 1) {
            j0n = rdli(mo, i + 1);
            int degn = rdli(me, i + 1) - j0n;
            int idn = j0n + lane;
            evn = edges[idn];
            if (lane < degn) {
                float2 v = xs2[evn];
                pxn = v.x; pyn = v.y;
            }
        }
        float px = pxv, py = pyv;
        for (int jj = j0 + 64 + lane; jj < j0 + deg; jj += 64) {   // rare deg>64 tail
            float2 v = xs2[edges[jj]];
            px += v.x; py += v.y;
        }
#pragma unroll
        for (int o = 1; o < 64; o <<= 1) {
            px += __shfl_xor(px, o, 64);
            py += __shfl_xor(py, o, 64);
        }
        float gx = dn * (px + rdlf(sxx, i));
        float gy = dn * (py + rdlf(sxy, i));
        float h = gx * w1a + gy * w1b + bb;
        h = h > 0.0f ? h : 0.0f;
        float y0 = 0.0f, y1 = 0.0f, y2 = 0.0f, y3 = 0.0f;
#pragma unroll
        for (int t = 0; t < 16; ++t) {
            float4 w = wc[t];
            y0 = fmaf(rdlf(h, 4 * t + 0), w.x, y0);
            y1 = fmaf(rdlf(h, 4 * t + 1), w.y, y1);
            y2 = fmaf(rdlf(h, 4 * t + 2), w.z, y2);
            y3 = fmaf(rdlf(h, 4 * t + 3), w.w, y3);
        }
        Yout[n * 64 + lane] = __float2half(dn * ((y0 + y1) + (y2 + y3)));
        ev = evn; j0 = j0n; pxv = pxn; pyv = pyn;
    }
}

// ---------- layers 2/3: software-pipelined quad-row fp16 gather, 32-slot
//            prefetch. FINAL fuses the mean-pool accumulation (batch sorted):
//            run-accumulate per graph, atomic flush at graph boundaries. ----------
template<bool FINAL>
__global__ __launch_bounds__(256, 4)
void k_gl(const int* __restrict__ edges, const int* __restrict__ off,
          const int* __restrict__ endv, const float* __restrict__ dinv,
          const __half* __restrict__ Yin, const float* __restrict__ Wn,
          const float* __restrict__ bias, __half* __restrict__ Yout,
          const int* __restrict__ bat, float* __restrict__ sums,
          float* __restrict__ cnts) {
    const uint2* __restrict__ Yin2 = (const uint2*)Yin;   // 16 × 8B per 64-half row
    int lane = threadIdx.x & 63;
    int q = lane & 15, s = lane >> 4;          // sub-group: s = which row of a quad
    int wid = blockIdx.x * 4 + (threadIdx.x >> 6);
    int n0 = wid * CPW;
    if (n0 >= N_NODES) return;
    float bb = bias[lane];
    float4 wc[16];
    if (!FINAL) {
#pragma unroll
        for (int t = 0; t < 16; ++t) {
            wc[t].x = Wn[(4 * t + 0) * 64 + lane];
            wc[t].y = Wn[(4 * t + 1) * 64 + lane];
            wc[t].z = Wn[(4 * t + 2) * 64 + lane];
            wc[t].w = Wn[(4 * t + 3) * 64 + lane];
        }
#pragma unroll
        for (int t = 0; t < 16; ++t) {
            asm volatile("" : "+v"(wc[t].x), "+v"(wc[t].y), "+v"(wc[t].z), "+v"(wc[t].w));
        }
    }
    // chunk metadata in lanes 0..15 (FINAL also loads batch ids)
    int mo = 0, me = 0; float md = 0.0f; int bt = 0;
    if (lane < CPW) {
        int nn = n0 + lane;
        mo = off[nn]; me = endv[nn]; md = dinv[nn];
        if (FINAL) bt = bat[nn];
    }
    int j0 = rdli(mo, 0);
    int j1 = rdli(me, 0);
    int m0 = j1 - j0; if (m0 > 64) m0 = 64;
    int idx = j0 + lane;
    int ev = edges[idx];                         // edge-index vector, node 0
    uint2 sraw = make_uint2(0u, 0u);
    if (s == 0) sraw = Yin2[(size_t)n0 * 16 + q];   // self row (prescaled fp16)
    // prologue: prefetch node 0's first-32-edge rows (group guards wave-uniform)
    uint2 r0 = make_uint2(0u, 0u), r1 = r0, r2 = r0, r3 = r0;
    uint2 r4 = r0, r5 = r0, r6 = r0, r7 = r0;
    {
        int i0 = __shfl(ev, 0 + s, 64);
        int i1 = __shfl(ev, 4 + s, 64);
        int i2 = __shfl(ev, 8 + s, 64);
        int i3 = __shfl(ev, 12 + s, 64);
        int i4 = __shfl(ev, 16 + s, 64);
        int i5 = __shfl(ev, 20 + s, 64);
        int i6 = __shfl(ev, 24 + s, 64);
        int i7 = __shfl(ev, 28 + s, 64);
        if (m0 > 0)  r0 = Yin2[(size_t)i0 * 16 + q];
        if (m0 > 4)  r1 = Yin2[(size_t)i1 * 16 + q];
        if (m0 > 8)  r2 = Yin2[(size_t)i2 * 16 + q];
        if (m0 > 12) r3 = Yin2[(size_t)i3 * 16 + q];
        if (m0 > 16) r4 = Yin2[(size_t)i4 * 16 + q];
        if (m0 > 20) r5 = Yin2[(size_t)i5 * 16 + q];
        if (m0 > 24) r6 = Yin2[(size_t)i6 * 16 + q];
        if (m0 > 28) r7 = Yin2[(size_t)i7 * 16 + q];
    }
    // fused-pool running state (FINAL only)
    float accp = 0.0f; int cntp = 0; int gprev = rdli(bt, 0);
    for (int i = 0; i < CPW; ++i) {
        int n = n0 + i;
        float dn = rdlf(md, i);
        int deg = rdli(me, i) - j0;
        int m = m0;
        // next node's metadata + edge vector + self row (issue early)
        int evn = 0; int j0n = 0; int mn = 0;
        uint2 srn = make_uint2(0u, 0u);
        if (i < CPW - 1) {
            j0n = rdli(mo, i + 1);
            int j1n = rdli(me, i + 1);
            mn = j1n - j0n; if (mn > 64) mn = 64;
            int idn = j0n + lane;
            evn = edges[idn];
            if (s == 0) srn = Yin2[(size_t)(n + 1) * 16 + q];
        }
        // ---- accumulate prefetched first-32 rows (per-lane slot mask) ----
        float4 acc = make_float4(0.f, 0.f, 0.f, 0.f);
        if (s == 0) acc4h(acc, sraw);
        if (0 + s < m)  acc4h(acc, r0);
        if (4 + s < m)  acc4h(acc, r1);
        if (8 + s < m)  acc4h(acc, r2);
        if (12 + s < m) acc4h(acc, r3);
        if (16 + s < m) acc4h(acc, r4);
        if (20 + s < m) acc4h(acc, r5);
        if (24 + s < m) acc4h(acc, r6);
        if (28 + s < m) acc4h(acc, r7);
        // ---- remainder 32..m in-line (uniform group bound, per-lane mask) ----
        for (int t = 8; 4 * t < m; ++t) {
            int sl = 4 * t + s;
            int ii = __shfl(ev, sl, 64);
            uint2 rr = Yin2[(size_t)ii * 16 + q];
            if (sl < m) acc4h(acc, rr);
        }
        // ---- rare deg>64 tail (sub 0 only) ----
        for (int jj = 64; jj < deg; ++jj) {
            int sidx = edges[j0 + jj];
            if (s == 0) {
                uint2 rr = Yin2[(size_t)sidx * 16 + q];
                acc4h(acc, rr);
            }
        }
        // ---- PREFETCH next node's rows: results not used until next iter,
        //      so the vmcnt wait lands after the transform below ----
        if (i < CPW - 1) {
            int i0 = __shfl(evn, 0 + s, 64);
            int i1 = __shfl(evn, 4 + s, 64);
            int i2 = __shfl(evn, 8 + s, 64);
            int i3 = __shfl(evn, 12 + s, 64);
            int i4 = __shfl(evn, 16 + s, 64);
            int i5 = __shfl(evn, 20 + s, 64);
            int i6 = __shfl(evn, 24 + s, 64);
            int i7 = __shfl(evn, 28 + s, 64);
            r0 = make_uint2(0u, 0u); r1 = r0; r2 = r0; r3 = r0;
            r4 = r0; r5 = r0; r6 = r0; r7 = r0;
            if (mn > 0)  r0 = Yin2[(size_t)i0 * 16 + q];
            if (mn > 4)  r1 = Yin2[(size_t)i1 * 16 + q];
            if (mn > 8)  r2 = Yin2[(size_t)i2 * 16 + q];
            if (mn > 12) r3 = Yin2[(size_t)i3 * 16 + q];
            if (mn > 16) r4 = Yin2[(size_t)i4 * 16 + q];
            if (mn > 20) r5 = Yin2[(size_t)i5 * 16 + q];
            if (mn > 24) r6 = Yin2[(size_t)i6 * 16 + q];
            if (mn > 28) r7 = Yin2[(size_t)i7 * 16 + q];
        }
        // ---- combine the 4 sub-groups (long VALU stretch covers prefetch) ----
        acc.x += __shfl_xor(acc.x, 16, 64); acc.x += __shfl_xor(acc.x, 32, 64);
        acc.y += __shfl_xor(acc.y, 16, 64); acc.y += __shfl_xor(acc.y, 32, 64);
        acc.z += __shfl_xor(acc.z, 16, 64); acc.z += __shfl_xor(acc.z, 32, 64);
        acc.w += __shfl_xor(acc.w, 16, 64); acc.w += __shfl_xor(acc.w, 32, 64);
        // redistribute: channel-per-lane layout
        int srcl = lane >> 2;
        float c0 = __shfl(acc.x, srcl, 64);
        float c1 = __shfl(acc.y, srcl, 64);
        float c2 = __shfl(acc.z, srcl, 64);
        float c3 = __shfl(acc.w, srcl, 64);
        float lo = (lane & 1) ? c1 : c0;
        float hi = (lane & 1) ? c3 : c2;
        float sumc = (lane & 2) ? hi : lo;
        float h = dn * sumc + bb;
        h = h > 0.0f ? h : 0.0f;
        if (FINAL) {
            int g = rdli(bt, i);
            if (g != gprev) {                    // flush previous graph's run
                atomicAdd(&sums[(size_t)gprev * 64 + lane], accp);
                if (lane == 0) atomicAdd(&cnts[gprev], (float)cntp);
                accp = 0.0f; cntp = 0; gprev = g;
            }
            accp += h; ++cntp;
        } else {
            float y0 = 0.0f, y1 = 0.0f, y2 = 0.0f, y3 = 0.0f;
#pragma unroll
            for (int t2 = 0; t2 < 16; ++t2) {
                float4 w = wc[t2];
                y0 = fmaf(rdlf(h, 4 * t2 + 0), w.x, y0);
                y1 = fmaf(rdlf(h, 4 * t2 + 1), w.y, y1);
                y2 = fmaf(rdlf(h, 4 * t2 + 2), w.z, y2);
                y3 = fmaf(rdlf(h, 4 * t2 + 3), w.w, y3);
            }
            Yout[n * 64 + lane] = __float2half(dn * ((y0 + y1) + (y2 + y3)));
        }
        ev = evn; sraw = srn; j0 = j0n; m0 = mn;
    }
    if (FINAL) {                                 // flush the last run
        atomicAdd(&sums[(size_t)gprev * 64 + lane], accp);
        if (lane == 0) atomicAdd(&cnts[gprev], (float)cntp);
    }
}

// ---------- MLP head ----------
__global__ void k_head(const float* __restrict__ sums, const float* __restrict__ cnts,
                       const float* __restrict__ Wf1, const float* __restrict__ bf1,
                       const float* __restrict__ Wf2, const float* __restrict__ bf2,
                       float* __restrict__ out) {
    __shared__ float p[64];
    __shared__ float h[64];
    int g = blockIdx.x;
    int c = threadIdx.x;
    float cnt = cnts[g];
    cnt = cnt > 1.0f ? cnt : 1.0f;
    p[c] = sums[g * 64 + c] / cnt;
    __syncthreads();
    float s = bf1[c];
#pragma unroll
    for (int k = 0; k < 64; ++k) s += p[k] * Wf1[k * 64 + c];
    h[c] = s > 0.0f ? s : 0.0f;
    __syncthreads();
    if (c < N_CLASSES) {
        float o = bf2[c];
#pragma unroll
        for (int k = 0; k < 64; ++k) o += h[k] * Wf2[k * N_CLASSES + c];
        out[g * N_CLASSES + c] = o;
    }
}

extern "C" void kernel_launch(void* const* d_in, const int* in_sizes, int n_in,
                              void* d_out, int out_size, void* d_ws, size_t ws_size,
                              hipStream_t stream) {
    const float* x   = (const float*)d_in[0];
    const int*   ei  = (const int*)d_in[1];
    const int*   bat = (const int*)d_in[2];
    const float* W1  = (const float*)d_in[3];
    const float* b1  = (const float*)d_in[4];
    const float* W2  = (const float*)d_in[5];
    const float* b2  = (const float*)d_in[6];
    const float* W3  = (const float*)d_in[7];
    const float* b3  = (const float*)d_in[8];
    const float* Wf1 = (const float*)d_in[9];
    const float* bf1 = (const float*)d_in[10];
    const float* Wf2 = (const float*)d_in[11];
    const float* bf2 = (const float*)d_in[12];
    float* out = (float*)d_out;

    const int* src = ei;
    const int* dst = ei + N_EDGES;

    char* p = (char*)d_ws;
    __half* Ph   = (__half*)p;  p += (size_t)N_NODES * 64 * 2;   // fp16 prescaled (post-L1)
    __half* Qh   = (__half*)p;  p += (size_t)N_NODES * 64 * 2;   // fp16 prescaled (post-L2)
    int*   stage = (int*)p;     p += (size_t)NBUCK * BCAP * 4;   // fixed-slot buckets
    int*   edges = (int*)p;     p += (size_t)NBUCK * BCAP * 4;   // gapped CSR payload
    int*   off   = (int*)p;     p += (size_t)N_NODES * 4;
    int*   endv  = (int*)p;     p += (size_t)N_NODES * 4;
    float* dinv  = (float*)p;   p += (size_t)N_NODES * 4;
    float* xs2   = (float*)p;   p += (size_t)N_NODES * 2 * 4;
    int*   gcur  = (int*)p;     p += (size_t)1024 * 4;
    float* sums  = (float*)p;   p += (size_t)N_GRAPHS * 64 * 4;
    float* cnts  = (float*)p;   p += (size_t)N_GRAPHS * 4;

    hipMemsetAsync(sums, 0, (size_t)(N_GRAPHS * 64 + N_GRAPHS) * 4, stream);

    const int BT = 256;
    int gPart = (N_EDGES + PT_EDGES - 1) / PT_EDGES;             // 391

    // ---- CSR build (fixed-capacity fine buckets: no histogram/scan passes) ----
    k_init<<<1, 1024, 0, stream>>>(gcur);
    k_part<<<gPart, BT, 0, stream>>>(src, dst, gcur, stage);
    k_sort<<<NBUCK, 256, 0, stream>>>(stage, gcur, edges, off, endv, dinv,
                                      (const float2*)x, (float2*)xs2);

    // ---- layer 1 (pipelined gather x, W1, relu, fused W2 + prescale, fp16 out) ----
    k_l1<<<GLAYER, BT, 0, stream>>>(edges, off, endv, dinv, (const float2*)xs2,
                                    W1, b1, W2, Ph);

    // ---- layer 2 (pipelined fp16 quad gather + b2/relu + fused W3, fp16 out) ----
    k_gl<false><<<GLAYER, BT, 0, stream>>>(edges, off, endv, dinv, Ph, W3, b2, Qh,
                                           nullptr, nullptr, nullptr);

    // ---- layer 3 (pipelined fp16 quad gather + b3/relu + FUSED mean-pool) ----
    k_gl<true><<<GLAYER, BT, 0, stream>>>(edges, off, endv, dinv, Qh, nullptr, b3,
                                          nullptr, bat, sums, cnts);

    // ---- head ----
    k_head<<<N_GRAPHS, 64, 0, stream>>>(sums, cnts, Wf1, bf1, Wf2, bf2, out);
}